// Round 15
// baseline (211.580 us; speedup 1.0000x reference)
//
#include <hip/hip_runtime.h>
#include <math.h>

#define BS 2
#define QLEN 64
#define KLEN 64
#define NH 8
#define DKV 64
#define INNER 512
#define VOCAB 4096
#define CHUNKV 64
#define RS 130               // Cv stride (doubles), even -> 16B-aligned b128 reads
#define BUFD (CHUNKV * RS)   // 8320 doubles per buffer

typedef double vdbl4 __attribute__((ext_vector_type(4)));
typedef double vdbl2 __attribute__((ext_vector_type(2)));

// ---------------- workspace layout (bytes) ----------------
// qp    : [BS][64][INNER] double  @ 0        (512 KB)
// kp    : [BS][64][INNER] double  @ 512 KB   (512 KB)
// dnt   : [DKV][VOCAB]    double  @ 1 MB     (2 MB)   l2-normalized dict, transposed
// E     : [VOCAB][DKV]    float   @ 3 MB     (1 MB)   LN(dict) @ vq_o_w
// bestf : [16][64][64]    u64     @ 4 MB     (512 KB) atomicMax'd packed (val | 4095-v code)
// bhcnt : [16] int                @ 4.5 MB   (64 B)   per-bh done counters

// ======== prep: proj GEMM (blocks 0..1023) + dict (blocks 1024..2047) — r12 exact ========
__global__ __launch_bounds__(256) void k_prep(
    const float* __restrict__ q_in, const float* __restrict__ k_in,
    const float* __restrict__ qpe, const float* __restrict__ kpe,
    const float* __restrict__ wi,
    const float* __restrict__ vq, const float* __restrict__ g,
    const float* __restrict__ bta, const float* __restrict__ ow,
    double* __restrict__ qp, double* __restrict__ kp,
    double* __restrict__ dnt, float* __restrict__ E,
    unsigned long long* __restrict__ bestf, int* __restrict__ bhcnt)
{
    __shared__ double S[1600];           // proj: xs[1024]+red[512]; dict: Lsh[256]+Dsh[320]
    __shared__ float Osh[4096];          // dict: ow cache
    int bid = blockIdx.x;
    int t = threadIdx.x;

    if (bid < 1024) {
        int side = bid >> 9;
        int b    = (bid >> 8) & 1;
        int rp   = (bid >> 3) & 31;
        int cb   = bid & 7;
        const float* xin = side ? k_in : q_in;
        const float* pin = side ? kpe : qpe;
        double* outp = side ? kp : qp;
        int wrow0 = side ? INNER : 0;
        int r0 = rp * 2;
        double* xs = S;                  // [2][512]
        double* red = S + 1024;          // [dh*2+rr][64]
        for (int i = t; i < 2 * INNER; i += 256) {
            int rr = i >> 9, dd = i & 511;
            int gidx = (b * 64 + r0 + rr) * INNER + dd;
            xs[rr * INNER + dd] = (double)xin[gidx] + (double)pin[gidx];
        }
        __syncthreads();
        int col = cb * 64 + (t & 63);
        int dh = t >> 6;
        double a0 = 0.0, a1 = 0.0;
        #pragma unroll 8
        for (int d = dh * 128; d < dh * 128 + 128; ++d) {
            double w = (double)wi[(size_t)(wrow0 + d) * INNER + col];
            a0 = fma(xs[d], w, a0);
            a1 = fma(xs[INNER + d], w, a1);
        }
        red[(dh * 2 + 0) * 64 + (t & 63)] = a0;
        red[(dh * 2 + 1) * 64 + (t & 63)] = a1;
        __syncthreads();
        if (t < 128) {
            int rr = t >> 6, c2 = t & 63;
            double s = (red[(0 * 2 + rr) * 64 + c2] + red[(1 * 2 + rr) * 64 + c2])
                     + (red[(2 * 2 + rr) * 64 + c2] + red[(3 * 2 + rr) * 64 + c2]);
            outp[(size_t)(b * 64 + r0 + rr) * INNER + cb * 64 + c2] = s;
        }
    } else {
        int db = bid - 1024;             // 0..1023, 4 vocab rows each (1 per wave)
        if (db < 256) bestf[db * 256 + t] = 0ull;
        if (db == 0 && t < 16) bhcnt[t] = 0;
        double* Lsh = S;                 // [wave(4)][64] LN values
        double* Dsh = S + 256;           // [j(64)][5] dn staging (vloc = wave)
        int vb = db * 4;
        int wv = t >> 6, lane = t & 63;
        for (int i = t; i < 4096; i += 256) Osh[i] = ow[i];
        int v = vb + wv;
        double z = (double)vq[v * DKV + lane];
        double s2 = z * z, s1 = z;
        for (int m = 32; m >= 1; m >>= 1) { s2 += __shfl_xor(s2, m); s1 += __shfl_xor(s1, m); }
        Dsh[lane * 5 + wv] = z * (1.0 / sqrt(fmax(s2, 1e-12)));
        double mean = s1 * (1.0 / 64.0);
        double d0 = z - mean;
        double vv2 = d0 * d0;
        for (int m = 32; m >= 1; m >>= 1) vv2 += __shfl_xor(vv2, m);
        vv2 *= (1.0 / 64.0);
        Lsh[wv * 64 + lane] = d0 * (1.0 / sqrt(vv2 + 1e-6)) * (double)g[lane] + (double)bta[lane];
        __syncthreads();
        double c0 = 0.0, c1 = 0.0, c2 = 0.0, c3 = 0.0;
        #pragma unroll 4
        for (int gg = 0; gg < 16; ++gg) {
            int jj = gg * 4;
            c0 = fma(Lsh[wv * 64 + jj + 0], (double)Osh[(jj + 0) * 64 + lane], c0);
            c1 = fma(Lsh[wv * 64 + jj + 1], (double)Osh[(jj + 1) * 64 + lane], c1);
            c2 = fma(Lsh[wv * 64 + jj + 2], (double)Osh[(jj + 2) * 64 + lane], c2);
            c3 = fma(Lsh[wv * 64 + jj + 3], (double)Osh[(jj + 3) * 64 + lane], c3);
        }
        E[v * DKV + lane] = (float)((c0 + c1) + (c2 + c3));
        {
            int j = t >> 2, vloc = t & 3;
            dnt[(size_t)j * VOCAB + vb + vloc] = Dsh[j * 5 + vloc];
        }
    }
}

// ======== MFMA-f64 sim + packed max-plus scan + FENCE-FREE fused combine ========
// r12 pipeline exactly. Epilogue protocol: all cross-block data moves through
// device-scope atomics (bestf atomicMax; bhcnt atomicAdd); __syncthreads drains
// vmcnt(0), so the block's atomics are complete at the coherent point before
// the counter increment — NO __threadfence (r13's buffer_wbl2 per block was
// the 3x regression). Last block per bh runs the combine (r13-verified code),
// reading bestf via atomicMax(p,0) coherent reads.
__global__ __launch_bounds__(1024, 4) void k_simscan(
    const double* __restrict__ qp, const double* __restrict__ kp,
    const double* __restrict__ dnt,
    unsigned long long* __restrict__ bestf, int* __restrict__ bhcnt,
    const float* __restrict__ E,
    const float* __restrict__ lng, const float* __restrict__ lnb,
    float* __restrict__ out)
{
    int bid = blockIdx.x;             // 256 = cg(16) x bh(16)
    int bh = bid & 15, cg = bid >> 4;
    int b = bh >> 3, h = bh & 7;
    int t = threadIdx.x;
    int w = t >> 6, l = t & 63;

    __shared__ double S[2 * BUFD];    // 133120 B -> 1 block/CU
    __shared__ int lastdone;

    int asub = l >> 4;
    int lrow = l & 15;
    bool isprod = (w < 8);

    // ---- D-layout probes (verified calibration, rounds 6-14) ----
    int drow[4], dcol[4];
    {
        vdbl4 prow = (vdbl4){0.0, 0.0, 0.0, 0.0};
        vdbl4 pcol = (vdbl4){0.0, 0.0, 0.0, 0.0};
        double a_row = (asub == 0) ? (double)lrow : 0.0;
        double b_one = (asub == 0) ? 1.0 : 0.0;
        double a_one = (asub == 0) ? 1.0 : 0.0;
        double b_col = (asub == 0) ? (double)lrow : 0.0;
        prow = __builtin_amdgcn_mfma_f64_16x16x4f64(a_row, b_one, prow, 0, 0, 0);
        pcol = __builtin_amdgcn_mfma_f64_16x16x4f64(a_one, b_col, pcol, 0, 0, 0);
        #pragma unroll
        for (int r = 0; r < 4; ++r) { drow[r] = (int)prow[r]; dcol[r] = (int)pcol[r]; }
    }

    // ---- producer state: A-frags for 1 row-tile x 16 ksteps (loaded once) ----
    double afr[16];
    if (isprod) {
        const double* src = (w < 4) ? qp : kp;
        int arow = (w & 3) * 16 + lrow;
        #pragma unroll
        for (int ks = 0; ks < 16; ++ks)
            afr[ks] = src[(size_t)(b * 64 + arow) * INNER + h * 64 + ks * 4 + asub];
    }

    // ---- consumer state (waves 8-15): 8 pairs q in {qg+16i}, k in {kg+32j} ----
    int ci = t - 512;
    int qg = ci & 15, kg = (ci >> 4) & 31;
    double best[4][2];
    #pragma unroll
    for (int i = 0; i < 4; ++i)
        #pragma unroll
        for (int j = 0; j < 2; ++j) best[i][j] = 0.0;

    for (int step = 0; step < 5; ++step) {
        if (isprod && step < 4) {
            int v0 = (cg * 4 + step) * CHUNKV;
            double* buf = S + (step & 1) * BUFD;
            vdbl4 acc[4];
            #pragma unroll
            for (int vt = 0; vt < 4; ++vt) acc[vt] = (vdbl4){0.0, 0.0, 0.0, 0.0};
            size_t base = (size_t)asub * VOCAB + v0 + lrow;
            double bcur[4], bnext[4];
            #pragma unroll
            for (int vt = 0; vt < 4; ++vt) bcur[vt] = dnt[base + vt * 16];
            #pragma unroll
            for (int ks = 0; ks < 16; ++ks) {
                if (ks < 15) {
                    size_t krow = base + (size_t)((ks + 1) * 4) * VOCAB;
                    #pragma unroll
                    for (int vt = 0; vt < 4; ++vt) bnext[vt] = dnt[krow + vt * 16];
                }
                #pragma unroll
                for (int vt = 0; vt < 4; ++vt)
                    acc[vt] = __builtin_amdgcn_mfma_f64_16x16x4f64(
                        afr[ks], bcur[vt], acc[vt], 0, 0, 0);
                if (ks < 15) {
                    #pragma unroll
                    for (int vt = 0; vt < 4; ++vt) bcur[vt] = bnext[vt];
                }
            }
            // pack: affine to [1.25,1.75], clear low 13 bits, embed (4095-v)<<1 on q
            // side; store at PERMUTED slot so consumer reads are contiguous b128.
            bool isq = (w < 4);
            #pragma unroll
            for (int vt = 0; vt < 4; ++vt)
                #pragma unroll
                for (int r = 0; r < 4; ++r) {
                    int vl = vt * 16 + dcol[r];
                    int grow = (w & 3) * 16 + drow[r];     // global row 0..63 within side
                    int slot = isq ? ((grow & 15) * 4 + (grow >> 4))
                                   : (64 + (grow & 31) * 2 + (grow >> 5));
                    unsigned long long code =
                        (unsigned long long)((4095 - (v0 + vl)) << 1);
                    double s = fma(acc[vt][r], 1.0 / 64.0, 1.5);
                    unsigned long long bb2 = __double_as_longlong(s) & ~0x1FFFull;
                    if (isq) bb2 |= code;
                    buf[vl * RS + slot] = __longlong_as_double(bb2);
                }
        }
        if (!isprod && step >= 1) {
            double* buf = S + ((step - 1) & 1) * BUFD;
            #pragma unroll 2
            for (int v = 0; v < CHUNKV; ++v) {
                vdbl2 q01 = *(const vdbl2*)&buf[v * RS + qg * 4];       // q = qg, qg+16
                vdbl2 q23 = *(const vdbl2*)&buf[v * RS + qg * 4 + 2];   // q = qg+32, qg+48
                vdbl2 k01 = *(const vdbl2*)&buf[v * RS + 64 + kg * 2];  // k = kg, kg+32
                best[0][0] = fmax(best[0][0], q01[0] + k01[0]);
                best[0][1] = fmax(best[0][1], q01[0] + k01[1]);
                best[1][0] = fmax(best[1][0], q01[1] + k01[0]);
                best[1][1] = fmax(best[1][1], q01[1] + k01[1]);
                best[2][0] = fmax(best[2][0], q23[0] + k01[0]);
                best[2][1] = fmax(best[2][1], q23[0] + k01[1]);
                best[3][0] = fmax(best[3][0], q23[1] + k01[0]);
                best[3][1] = fmax(best[3][1], q23[1] + k01[1]);
            }
        }
        if (step < 4) __syncthreads();
    }

    if (!isprod) {
        #pragma unroll
        for (int i = 0; i < 4; ++i)
            #pragma unroll
            for (int j = 0; j < 2; ++j) {
                int q = qg + 16 * i, k = kg + 32 * j;
                // positive doubles: bit order == numeric order; max order-independent
                atomicMax(&bestf[((size_t)bh * 64 + q) * 64 + k],
                          (unsigned long long)__double_as_longlong(best[i][j]));
            }
    }

    // ---- fence-free fused combine: __syncthreads drains vmcnt(0), so this
    // block's device-scope atomics are complete before the counter bump. ----
    __syncthreads();
    if (t == 0) lastdone = (atomicAdd(&bhcnt[bh], 1) == 15);
    __syncthreads();
    if (!lastdone) return;

    double* qs_l = S;                    // [64][65]
    double* ks_l = S + 4160;             // [64][65]
    float*  ws_l  = (float*)(S + 8320);  // [64][64]
    int*    idx_l = (int*)(S + 8320 + 2048);
    double* qn_l  = S + 8320 + 4096;     // [64]
    double* kn_l  = S + 8320 + 4160;     // [64]

    for (int i = t; i < 8192; i += 1024) {
        int row = i >> 6, d = i & 63;
        if (row < 64) qs_l[row * 65 + d] = qp[(size_t)(b * 64 + row) * INNER + h * 64 + d];
        else ks_l[(row - 64) * 65 + d] = kp[(size_t)(b * 64 + row - 64) * INNER + h * 64 + d];
    }
    __syncthreads();
    if (t < 128) {
        int r = t & 63;
        const double* src = (t < 64) ? (qs_l + r * 65) : (ks_l + r * 65);
        double s = 0.0;
        for (int d = 0; d < 64; ++d) s = fma(src[d], src[d], s);
        if (t < 64) qn_l[r] = s; else kn_l[r] = s;
    }
    __syncthreads();

    #pragma unroll
    for (int i = 0; i < 4; ++i) {        // 4 (q,k) pairs per thread
        int p = t + i * 1024;
        int q = p >> 6, k = p & 63;
        double gd = 0.0;
        for (int d = 0; d < 64; ++d) gd = fma(qs_l[q * 65 + d], ks_l[k * 65 + d], gd);
        // device-scope atomic read: coherent view of all 16 blocks' maxes
        unsigned long long bb = atomicMax(&bestf[((size_t)bh * 64 + q) * 64 + k], 0ull);
        int vidx = 4095 - (int)(bb & 0xFFFull);
        double sval = __longlong_as_double(bb & ~0x1FFFull);
        double tru = (sval - 3.0) * 64.0;
        double n2 = qn_l[q] + kn_l[k] + 2.0 * gd;
        double wsim = tru * (1.0 / sqrt(fmax(n2, 1e-12)));
        size_t oidx = ((size_t)(b * QLEN + q) * KLEN + k) * NH + h;
        out[65536 + oidx] = (float)vidx;          // out_ids as float32
        out[131072 + oidx] = (float)wsim;         // r3_scores
        ws_l[q * 64 + k] = (float)wsim;
        idx_l[q * 64 + k] = vidx;
    }
    __syncthreads();

    #pragma unroll
    for (int i = 0; i < 4; ++i) {        // 4 (q,d) items per thread; q wave-uniform
        int item = t + i * 1024;
        int q = item >> 6, d = item & 63;
        float acc = 0.0f;
        #pragma unroll 4
        for (int k2 = 0; k2 < 64; ++k2)
            acc += E[idx_l[q * 64 + k2] * DKV + d] * ws_l[q * 64 + k2];
        acc *= (1.0f / 64.0f);
        float mean = acc;
        for (int m = 32; m >= 1; m >>= 1) mean += __shfl_xor(mean, m);
        mean *= (1.0f / 64.0f);
        float dv = acc - mean;
        float var = dv * dv;
        for (int m = 32; m >= 1; m >>= 1) var += __shfl_xor(var, m);
        var *= (1.0f / 64.0f);
        float o = dv * rsqrtf(var + 1e-6f) * lng[d] + lnb[d];
        out[(((size_t)b * NH + h) * QLEN + q) * DKV + d] = o;
    }
}

extern "C" void kernel_launch(void* const* d_in, const int* in_sizes, int n_in,
                              void* d_out, int out_size, void* d_ws, size_t ws_size,
                              hipStream_t stream) {
    const float* query = (const float*)d_in[0];
    const float* key   = (const float*)d_in[1];
    const float* qpe   = (const float*)d_in[2];
    const float* kpe   = (const float*)d_in[3];
    const float* wi    = (const float*)d_in[4];
    const float* vq    = (const float*)d_in[5];
    const float* vqg   = (const float*)d_in[6];
    const float* vqb   = (const float*)d_in[7];
    const float* ow    = (const float*)d_in[8];
    const float* lng   = (const float*)d_in[9];
    const float* lnb   = (const float*)d_in[10];
    float* out = (float*)d_out;

    char* ws = (char*)d_ws;
    double* qp  = (double*)(ws + 0);
    double* kp  = (double*)(ws + 524288);
    double* dnt = (double*)(ws + 1048576);
    float*  E   = (float*) (ws + 3145728);
    unsigned long long* bestf = (unsigned long long*)(ws + 4194304);
    int* bhcnt = (int*)(ws + 4718592);

    k_prep   <<<2048, 256, 0, stream>>>(query, key, qpe, kpe, wi, vq, vqg, vqb, ow,
                                        qp, kp, dnt, E, bestf, bhcnt);
    k_simscan<<<256, 1024, 0, stream>>>(qp, kp, dnt, bestf, bhcnt, E, lng, lnb, out);
}

// Round 16
// 152.941 us; speedup vs baseline: 1.3834x; 1.3834x over previous
//
#include <hip/hip_runtime.h>
#include <math.h>

#define BS 2
#define QLEN 64
#define KLEN 64
#define NH 8
#define DKV 64
#define INNER 512
#define VOCAB 4096
#define CHUNKV 64
#define RS 130               // Cv stride (doubles), even -> 16B-aligned b128 reads
#define BUFD (CHUNKV * RS)   // 8320 doubles per buffer

typedef double vdbl4 __attribute__((ext_vector_type(4)));
typedef double vdbl2 __attribute__((ext_vector_type(2)));

// ---------------- workspace layout (bytes) ----------------
// qp    : [BS][64][INNER] double  @ 0        (512 KB)
// kp    : [BS][64][INNER] double  @ 512 KB   (512 KB)
// dnt   : [DKV][VOCAB]    double  @ 1 MB     (2 MB)   l2-normalized dict, transposed
// E     : [VOCAB][DKV]    float   @ 3 MB     (1 MB)   LN(dict) @ vq_o_w
// bestf : [16][64][64]    u64     @ 4 MB     (512 KB) atomicMax'd packed (val | 4095-v code)

// ======== prep: proj GEMM (blocks 0..1023) + dict (blocks 1024..2047) — r12 exact ========
__global__ __launch_bounds__(256) void k_prep(
    const float* __restrict__ q_in, const float* __restrict__ k_in,
    const float* __restrict__ qpe, const float* __restrict__ kpe,
    const float* __restrict__ wi,
    const float* __restrict__ vq, const float* __restrict__ g,
    const float* __restrict__ bta, const float* __restrict__ ow,
    double* __restrict__ qp, double* __restrict__ kp,
    double* __restrict__ dnt, float* __restrict__ E,
    unsigned long long* __restrict__ bestf)
{
    __shared__ double S[1600];           // proj: xs[1024]+red[512]; dict: Lsh[256]+Dsh[320]
    __shared__ float Osh[4096];          // dict: ow cache
    int bid = blockIdx.x;
    int t = threadIdx.x;

    if (bid < 1024) {
        int side = bid >> 9;
        int b    = (bid >> 8) & 1;
        int rp   = (bid >> 3) & 31;
        int cb   = bid & 7;
        const float* xin = side ? k_in : q_in;
        const float* pin = side ? kpe : qpe;
        double* outp = side ? kp : qp;
        int wrow0 = side ? INNER : 0;
        int r0 = rp * 2;
        double* xs = S;                  // [2][512]
        double* red = S + 1024;          // [dh*2+rr][64]
        for (int i = t; i < 2 * INNER; i += 256) {
            int rr = i >> 9, dd = i & 511;
            int gidx = (b * 64 + r0 + rr) * INNER + dd;
            xs[rr * INNER + dd] = (double)xin[gidx] + (double)pin[gidx];
        }
        __syncthreads();
        int col = cb * 64 + (t & 63);
        int dh = t >> 6;
        double a0 = 0.0, a1 = 0.0;
        #pragma unroll 8
        for (int d = dh * 128; d < dh * 128 + 128; ++d) {
            double w = (double)wi[(size_t)(wrow0 + d) * INNER + col];
            a0 = fma(xs[d], w, a0);
            a1 = fma(xs[INNER + d], w, a1);
        }
        red[(dh * 2 + 0) * 64 + (t & 63)] = a0;
        red[(dh * 2 + 1) * 64 + (t & 63)] = a1;
        __syncthreads();
        if (t < 128) {
            int rr = t >> 6, c2 = t & 63;
            double s = (red[(0 * 2 + rr) * 64 + c2] + red[(1 * 2 + rr) * 64 + c2])
                     + (red[(2 * 2 + rr) * 64 + c2] + red[(3 * 2 + rr) * 64 + c2]);
            outp[(size_t)(b * 64 + r0 + rr) * INNER + cb * 64 + c2] = s;
        }
    } else {
        int db = bid - 1024;             // 0..1023, 4 vocab rows each (1 per wave)
        if (db < 256) bestf[db * 256 + t] = 0ull;
        double* Lsh = S;                 // [wave(4)][64] LN values
        double* Dsh = S + 256;           // [j(64)][5] dn staging (vloc = wave)
        int vb = db * 4;
        int wv = t >> 6, lane = t & 63;
        for (int i = t; i < 4096; i += 256) Osh[i] = ow[i];
        int v = vb + wv;
        double z = (double)vq[v * DKV + lane];
        double s2 = z * z, s1 = z;
        for (int m = 32; m >= 1; m >>= 1) { s2 += __shfl_xor(s2, m); s1 += __shfl_xor(s1, m); }
        Dsh[lane * 5 + wv] = z * (1.0 / sqrt(fmax(s2, 1e-12)));
        double mean = s1 * (1.0 / 64.0);
        double d0 = z - mean;
        double vv2 = d0 * d0;
        for (int m = 32; m >= 1; m >>= 1) vv2 += __shfl_xor(vv2, m);
        vv2 *= (1.0 / 64.0);
        Lsh[wv * 64 + lane] = d0 * (1.0 / sqrt(vv2 + 1e-6)) * (double)g[lane] + (double)bta[lane];
        __syncthreads();
        double c0 = 0.0, c1 = 0.0, c2 = 0.0, c3 = 0.0;
        #pragma unroll 4
        for (int gg = 0; gg < 16; ++gg) {
            int jj = gg * 4;
            c0 = fma(Lsh[wv * 64 + jj + 0], (double)Osh[(jj + 0) * 64 + lane], c0);
            c1 = fma(Lsh[wv * 64 + jj + 1], (double)Osh[(jj + 1) * 64 + lane], c1);
            c2 = fma(Lsh[wv * 64 + jj + 2], (double)Osh[(jj + 2) * 64 + lane], c2);
            c3 = fma(Lsh[wv * 64 + jj + 3], (double)Osh[(jj + 3) * 64 + lane], c3);
        }
        E[v * DKV + lane] = (float)((c0 + c1) + (c2 + c3));
        {
            int j = t >> 2, vloc = t & 3;
            dnt[(size_t)j * VOCAB + vb + vloc] = Dsh[j * 5 + vloc];
        }
    }
}

// ======== producer/consumer MFMA-f64 sim + scan — LDS-semaphore sync ========
// r12 pipeline, but the per-step __syncthreads is replaced by LDS atomic
// counters: producers signal prod_cnt[s] after packing chunk s; consumers
// spin on it, scan, then signal cons_cnt[s]; producer of step s waits on
// cons_cnt[s-2] (2-buffer reuse). NO s_barrier in the loop -> producers never
// drain their in-flight global prefetches at chunk boundaries (the r10-
// diagnosed stall). __threadfence_block = LDS-scope only (cheap; NOT r13's
// L2 writeback). Deadlock-free: monotonic counters, acyclic waits.
__global__ __launch_bounds__(1024, 4) void k_simscan(
    const double* __restrict__ qp, const double* __restrict__ kp,
    const double* __restrict__ dnt,
    unsigned long long* __restrict__ bestf)
{
    int bid = blockIdx.x;             // 256 = cg(16) x bh(16)
    int bh = bid & 15, cg = bid >> 4;
    int b = bh >> 3, h = bh & 7;
    int t = threadIdx.x;
    int w = t >> 6, l = t & 63;

    __shared__ double S[2 * BUFD];    // 133120 B -> 1 block/CU
    __shared__ int sem[8];            // [0..3]=prod_cnt, [4..7]=cons_cnt

    int asub = l >> 4;
    int lrow = l & 15;
    bool isprod = (w < 8);

    if (t < 8) sem[t] = 0;

    // ---- D-layout probes (verified calibration, rounds 6-15) ----
    int drow[4], dcol[4];
    {
        vdbl4 prow = (vdbl4){0.0, 0.0, 0.0, 0.0};
        vdbl4 pcol = (vdbl4){0.0, 0.0, 0.0, 0.0};
        double a_row = (asub == 0) ? (double)lrow : 0.0;
        double b_one = (asub == 0) ? 1.0 : 0.0;
        double a_one = (asub == 0) ? 1.0 : 0.0;
        double b_col = (asub == 0) ? (double)lrow : 0.0;
        prow = __builtin_amdgcn_mfma_f64_16x16x4f64(a_row, b_one, prow, 0, 0, 0);
        pcol = __builtin_amdgcn_mfma_f64_16x16x4f64(a_one, b_col, pcol, 0, 0, 0);
        #pragma unroll
        for (int r = 0; r < 4; ++r) { drow[r] = (int)prow[r]; dcol[r] = (int)pcol[r]; }
    }

    // ---- producer state: A-frags for 1 row-tile x 16 ksteps (loaded once) ----
    double afr[16];
    if (isprod) {
        const double* src = (w < 4) ? qp : kp;
        int arow = (w & 3) * 16 + lrow;
        #pragma unroll
        for (int ks = 0; ks < 16; ++ks)
            afr[ks] = src[(size_t)(b * 64 + arow) * INNER + h * 64 + ks * 4 + asub];
    }

    // ---- consumer state (waves 8-15): 8 pairs q in {qg+16i}, k in {kg+32j} ----
    int ci = t - 512;
    int qg = ci & 15, kg = (ci >> 4) & 31;
    double best[4][2];
    #pragma unroll
    for (int i = 0; i < 4; ++i)
        #pragma unroll
        for (int j = 0; j < 2; ++j) best[i][j] = 0.0;

    __syncthreads();                  // sem init visible to all (only barrier)

    if (isprod) {
        for (int step = 0; step < 4; ++step) {
            if (step >= 2) {          // wait: consumers done with buf[step&1]
                for (;;) {
                    int c0 = 0;
                    if (l == 0) c0 = atomicAdd(&sem[4 + step - 2], 0);
                    if (__shfl(c0, 0) >= 8) break;
                    __builtin_amdgcn_s_sleep(2);
                }
            }
            int v0 = (cg * 4 + step) * CHUNKV;
            double* buf = S + (step & 1) * BUFD;
            vdbl4 acc[4];
            #pragma unroll
            for (int vt = 0; vt < 4; ++vt) acc[vt] = (vdbl4){0.0, 0.0, 0.0, 0.0};
            size_t base = (size_t)asub * VOCAB + v0 + lrow;
            double bcur[4], bnext[4];
            #pragma unroll
            for (int vt = 0; vt < 4; ++vt) bcur[vt] = dnt[base + vt * 16];
            #pragma unroll
            for (int ks = 0; ks < 16; ++ks) {
                if (ks < 15) {
                    size_t krow = base + (size_t)((ks + 1) * 4) * VOCAB;
                    #pragma unroll
                    for (int vt = 0; vt < 4; ++vt) bnext[vt] = dnt[krow + vt * 16];
                }
                #pragma unroll
                for (int vt = 0; vt < 4; ++vt)
                    acc[vt] = __builtin_amdgcn_mfma_f64_16x16x4f64(
                        afr[ks], bcur[vt], acc[vt], 0, 0, 0);
                if (ks < 15) {
                    #pragma unroll
                    for (int vt = 0; vt < 4; ++vt) bcur[vt] = bnext[vt];
                }
            }
            // pack: affine to [1.25,1.75], clear low 13 bits, embed (4095-v)<<1 on q
            // side; store at PERMUTED slot so consumer reads are contiguous b128.
            bool isq = (w < 4);
            #pragma unroll
            for (int vt = 0; vt < 4; ++vt)
                #pragma unroll
                for (int r = 0; r < 4; ++r) {
                    int vl = vt * 16 + dcol[r];
                    int grow = (w & 3) * 16 + drow[r];     // global row 0..63 within side
                    int slot = isq ? ((grow & 15) * 4 + (grow >> 4))
                                   : (64 + (grow & 31) * 2 + (grow >> 5));
                    unsigned long long code =
                        (unsigned long long)((4095 - (v0 + vl)) << 1);
                    double s = fma(acc[vt][r], 1.0 / 64.0, 1.5);
                    unsigned long long bb2 = __double_as_longlong(s) & ~0x1FFFull;
                    if (isq) bb2 |= code;
                    buf[vl * RS + slot] = __longlong_as_double(bb2);
                }
            __threadfence_block();    // LDS writes committed before signal
            if (l == 0) atomicAdd(&sem[step], 1);
        }
    } else {
        for (int step = 0; step < 4; ++step) {
            for (;;) {                // wait: all 8 producers packed chunk step
                int c0 = 0;
                if (l == 0) c0 = atomicAdd(&sem[step], 0);
                if (__shfl(c0, 0) >= 8) break;
                __builtin_amdgcn_s_sleep(2);
            }
            double* buf = S + (step & 1) * BUFD;
            #pragma unroll 2
            for (int v = 0; v < CHUNKV; ++v) {
                vdbl2 q01 = *(const vdbl2*)&buf[v * RS + qg * 4];       // q = qg, qg+16
                vdbl2 q23 = *(const vdbl2*)&buf[v * RS + qg * 4 + 2];   // q = qg+32, qg+48
                vdbl2 k01 = *(const vdbl2*)&buf[v * RS + 64 + kg * 2];  // k = kg, kg+32
                best[0][0] = fmax(best[0][0], q01[0] + k01[0]);
                best[0][1] = fmax(best[0][1], q01[0] + k01[1]);
                best[1][0] = fmax(best[1][0], q01[1] + k01[0]);
                best[1][1] = fmax(best[1][1], q01[1] + k01[1]);
                best[2][0] = fmax(best[2][0], q23[0] + k01[0]);
                best[2][1] = fmax(best[2][1], q23[0] + k01[1]);
                best[3][0] = fmax(best[3][0], q23[1] + k01[0]);
                best[3][1] = fmax(best[3][1], q23[1] + k01[1]);
            }
            __threadfence_block();    // ds_reads complete before freeing buffer
            if (l == 0) atomicAdd(&sem[4 + step], 1);
        }
        #pragma unroll
        for (int i = 0; i < 4; ++i)
            #pragma unroll
            for (int j = 0; j < 2; ++j) {
                int q = qg + 16 * i, k = kg + 32 * j;
                // positive doubles: bit order == numeric order; max order-independent
                atomicMax(&bestf[((size_t)bh * 64 + q) * 64 + k],
                          (unsigned long long)__double_as_longlong(best[i][j]));
            }
    }
}

// ======== combine (r12 exact): 1024 blocks = q(64) x bh(16) ========
__global__ __launch_bounds__(256) void k_combine(
    const unsigned long long* __restrict__ bestf,
    const double* __restrict__ qp, const double* __restrict__ kp,
    const float* __restrict__ E,
    const float* __restrict__ lng, const float* __restrict__ lnb,
    float* __restrict__ out)
{
    int bid = blockIdx.x;             // 1024 = q(64) x bh(16)
    int bh = bid & 15, q = bid >> 4;
    int b = bh >> 3, h = bh & 7;
    int t = threadIdx.x;
    int w = t >> 6, lane = t & 63;

    __shared__ double qrow[64];
    __shared__ double gpart[4][64];
    __shared__ double knpart[4][64];
    __shared__ double qnpart[4];
    __shared__ float  ws_l[64];
    __shared__ int    idx_l[64];
    __shared__ float  epart[4][64];

    if (t < 64) qrow[t] = qp[(size_t)(b * 64 + q) * INNER + h * 64 + t];
    __syncthreads();

    {
        const double* krow = kp + (size_t)(b * 64 + lane) * INNER + h * 64 + w * 16;
        double gd = 0.0, kn = 0.0;
        #pragma unroll
        for (int i = 0; i < 16; ++i) {
            double xk = krow[i];
            gd = fma(qrow[w * 16 + i], xk, gd);
            kn = fma(xk, xk, kn);
        }
        gpart[w][lane] = gd;
        knpart[w][lane] = kn;
        if (lane == 0) {
            double qn = 0.0;
            #pragma unroll
            for (int i = 0; i < 16; ++i) { double xq = qrow[w * 16 + i]; qn = fma(xq, xq, qn); }
            qnpart[w] = qn;
        }
    }
    __syncthreads();

    if (w == 0) {
        int k = lane;
        double gdot = (gpart[0][k] + gpart[1][k]) + (gpart[2][k] + gpart[3][k]);
        double kn2  = (knpart[0][k] + knpart[1][k]) + (knpart[2][k] + knpart[3][k]);
        double qn2  = (qnpart[0] + qnpart[1]) + (qnpart[2] + qnpart[3]);
        unsigned long long bb = bestf[((size_t)bh * 64 + q) * 64 + k];
        int vidx = 4095 - (int)(bb & 0xFFFull);
        double sval = __longlong_as_double(bb & ~0x1FFFull);
        double tru = (sval - 3.0) * 64.0;
        double n2 = qn2 + kn2 + 2.0 * gdot;
        double wsim = tru * (1.0 / sqrt(fmax(n2, 1e-12)));
        size_t oidx = ((size_t)(b * QLEN + q) * KLEN + k) * NH + h;
        out[65536 + oidx] = (float)vidx;          // out_ids as float32
        out[131072 + oidx] = (float)wsim;         // r3_scores
        ws_l[k] = (float)wsim;
        idx_l[k] = vidx;
    }
    __syncthreads();

    {
        int d = lane;
        float acc = 0.0f;
        #pragma unroll 4
        for (int k2 = w * 16; k2 < w * 16 + 16; ++k2)
            acc += E[idx_l[k2] * DKV + d] * ws_l[k2];
        epart[w][d] = acc;
    }
    __syncthreads();

    if (w == 0) {
        int d = lane;
        float acc = ((epart[0][d] + epart[1][d]) + (epart[2][d] + epart[3][d])) * (1.0f / 64.0f);
        float mean = acc;
        for (int m = 32; m >= 1; m >>= 1) mean += __shfl_xor(mean, m);
        mean *= (1.0f / 64.0f);
        float dv = acc - mean;
        float var = dv * dv;
        for (int m = 32; m >= 1; m >>= 1) var += __shfl_xor(var, m);
        var *= (1.0f / 64.0f);
        float o = dv * rsqrtf(var + 1e-6f) * lng[d] + lnb[d];
        out[(((size_t)b * NH + h) * QLEN + q) * DKV + d] = o;
    }
}

extern "C" void kernel_launch(void* const* d_in, const int* in_sizes, int n_in,
                              void* d_out, int out_size, void* d_ws, size_t ws_size,
                              hipStream_t stream) {
    const float* query = (const float*)d_in[0];
    const float* key   = (const float*)d_in[1];
    const float* qpe   = (const float*)d_in[2];
    const float* kpe   = (const float*)d_in[3];
    const float* wi    = (const float*)d_in[4];
    const float* vq    = (const float*)d_in[5];
    const float* vqg   = (const float*)d_in[6];
    const float* vqb   = (const float*)d_in[7];
    const float* ow    = (const float*)d_in[8];
    const float* lng   = (const float*)d_in[9];
    const float* lnb   = (const float*)d_in[10];
    float* out = (float*)d_out;

    char* ws = (char*)d_ws;
    double* qp  = (double*)(ws + 0);
    double* kp  = (double*)(ws + 524288);
    double* dnt = (double*)(ws + 1048576);
    float*  E   = (float*) (ws + 3145728);
    unsigned long long* bestf = (unsigned long long*)(ws + 4194304);

    k_prep   <<<2048, 256, 0, stream>>>(query, key, qpe, kpe, wi, vq, vqg, vqb, ow,
                                        qp, kp, dnt, E, bestf);
    k_simscan<<<256, 1024, 0, stream>>>(qp, kp, dnt, bestf);
    k_combine<<<1024, 256, 0, stream>>>(bestf, qp, kp, E, lng, lnb, out);
}